// Round 15
// baseline (264.264 us; speedup 1.0000x reference)
//
#include <hip/hip_runtime.h>

#define M_TETS 10240
#define N_NODES 2048
#define NPH 60
#define NBLK 32
#define NTHR 320
#define ADJCAP 64
#define SPIN_CAP 50000000

typedef float f32x4 __attribute__((ext_vector_type(4)));

// ws float offsets
#define OFF_MBUF 12288     // blk6: 6*2048 at 0
#define OFF_YBUF 20480     // mbuf: 2048 x float4
#define OFF_GDOT 184320    // ybuf: 10240 x 4 x float4
#define OFF_CNT  184704    // gdot: 2 sets x 3 x 64
#define OFF_SLOT 186752    // cnt: 2048 u32
#define OFF_ADJ  186784    // slots: 32 u32
#define WS_ZERO  186784    // adj (2048*64 u32) needs no zeroing

// log(500), log(10000)
__device__ __constant__ float LOG_A_MIN_C = 6.2146080984221914f;
__device__ __constant__ float LOG_A_MAX_C = 9.2103403719761836f;

__device__ __forceinline__ void rel_fence() { __builtin_amdgcn_fence(__ATOMIC_RELEASE, "agent"); }
__device__ __forceinline__ void acq_fence() { __builtin_amdgcn_fence(__ATOMIC_ACQUIRE, "agent"); }
__device__ __forceinline__ unsigned aldu(const unsigned* p) {
    return __hip_atomic_load(p, __ATOMIC_RELAXED, __HIP_MEMORY_SCOPE_AGENT);
}
__device__ __forceinline__ float aldf(const float* p) {
    return __hip_atomic_load(p, __ATOMIC_RELAXED, __HIP_MEMORY_SCOPE_AGENT);
}
__device__ __forceinline__ void astf(float* p, float v) {
    __hip_atomic_store(p, v, __ATOMIC_RELAXED, __HIP_MEMORY_SCOPE_AGENT);
}
__device__ __forceinline__ void astu(unsigned* p, unsigned v) {
    __hip_atomic_store(p, v, __ATOMIC_RELAXED, __HIP_MEMORY_SCOPE_AGENT);
}

// coherence-point 16B ops (R12/R14-proven: observe remote agent-atomic and
// volatile stores across XCDs with no fences)
__device__ __forceinline__ f32x4 vload4(const float* p) {
    return *(volatile const f32x4*)p;
}
__device__ __forceinline__ void vstore4(float* p, f32x4 v) {
    *(volatile f32x4*)p = v;
}

// Flag barrier. FULL=true: full fences (setup only; flushes plain stores like
// adj). FULL=false: fence-free — in-loop shared data moves via volatile/atomic
// ops at the coherence point; release = s_waitcnt vmcnt(0) before flag store.
template<bool FULL>
__device__ __forceinline__ void flag_bar(unsigned* slots, unsigned tgt) {
    if (FULL) rel_fence();
    else asm volatile("s_waitcnt vmcnt(0)" ::: "memory");
    __syncthreads();
    if (threadIdx.x == 0) astu(&slots[blockIdx.x], tgt);
    if (threadIdx.x < NBLK) {
        int guard = 0;
        while (aldu(&slots[threadIdx.x]) < tgt && ++guard < SPIN_CAP) {}
    }
    __syncthreads();
    if (FULL) acq_fence();
    else asm volatile("" ::: "memory");
}

__device__ __forceinline__ void bfly3(float& a, float& b, float& c) {
#pragma unroll
    for (int off = 32; off > 0; off >>= 1) {
        a += __shfl_xor(a, off);
        b += __shfl_xor(b, off);
        c += __shfl_xor(c, off);
    }
}

// symmetric 3x3 apply: s6 = [00,01,02,11,12,22]
__device__ __forceinline__ void sym_apply(const float* s6, const float* v, float* out) {
    out[0] = s6[0]*v[0] + s6[1]*v[1] + s6[2]*v[2];
    out[1] = s6[1]*v[0] + s6[3]*v[1] + s6[4]*v[2];
    out[2] = s6[2]*v[0] + s6[4]*v[1] + s6[5]*v[2];
}

__device__ __forceinline__ void sym_inv(const float* s, float* o) {
    float a = s[0], b = s[1], c = s[2], d = s[3], e = s[4], f = s[5];
    float C00 = d*f - e*e, C01 = c*e - b*f, C02 = b*e - c*d;
    float id = 1.0f / (a*C00 + b*C01 + c*C02);
    o[0] = C00*id; o[1] = C01*id; o[2] = C02*id;
    o[3] = (a*f - c*c)*id; o[4] = (b*c - a*e)*id; o[5] = (a*d - b*b)*id;
}

__global__ void __launch_bounds__(NTHR, 1) pcg_kernel(
    const float* __restrict__ theta, const float* __restrict__ delta,
    const float* __restrict__ ra, const float* __restrict__ rs, const float* __restrict__ rv,
    const float* __restrict__ vol, const float* __restrict__ bvec,
    const int* __restrict__ tets, const int* __restrict__ boundary,
    float* __restrict__ xout, float* __restrict__ ws)
{
    const int tid = blockIdx.x * NTHR + threadIdx.x;   // element id, 10240 total
    const int lane = threadIdx.x & 63;
    __shared__ float sd[1];

    float*    blk6  = ws;
    float*    mbuf  = ws + OFF_MBUF;
    float*    ybuf  = ws + OFF_YBUF;
    float*    gdot  = ws + OFF_GDOT;
    unsigned* cnt   = (unsigned*)(ws + OFF_CNT);
    unsigned* slots = (unsigned*)(ws + OFF_SLOT);
    unsigned* adj   = (unsigned*)(ws + OFF_ADJ);

    // ---- element data -> registers (ws head pre-zeroed by hipMemsetAsync) ----
    float A[3][12], S[3][12], V[12];
    int nd4[4];
    float cae, cse, cve;
    {
        const int e = tid;
#pragma unroll
        for (int a = 0; a < 3; a++)
#pragma unroll
            for (int i = 0; i < 12; i++) {
                A[a][i] = ra[e * 36 + a * 12 + i];
                S[a][i] = rs[e * 36 + a * 12 + i];
            }
#pragma unroll
        for (int i = 0; i < 12; i++) V[i] = rv[e * 12 + i];
        const int4 t = reinterpret_cast<const int4*>(tets)[e];
        nd4[0] = t.x; nd4[1] = t.y; nd4[2] = t.z; nd4[3] = t.w;
        float la = theta[0] + delta[e];
        la = fminf(fmaxf(la, LOG_A_MIN_C), LOG_A_MAX_C);
        float al = expf(la);
        float v = vol[e];
        cae = v * al; cse = 2.0f * v * al; cve = 8.0f * v * al;
    }

    auto matvec = [&](const float* pe, float* y) {
#pragma unroll
        for (int t = 0; t < 12; t++) y[t] = 0.f;
#pragma unroll
        for (int a = 0; a < 3; a++) {
            float qa = 0.f, qs = 0.f;
#pragma unroll
            for (int t = 0; t < 12; t++) { qa += A[a][t] * pe[t]; qs += S[a][t] * pe[t]; }
            qa *= cae; qs *= cse;
#pragma unroll
            for (int t = 0; t < 12; t++) y[t] += qa * A[a][t] + qs * S[a][t];
        }
        float qv = 0.f;
#pragma unroll
        for (int t = 0; t < 12; t++) qv += V[t] * pe[t];
        qv *= cve;
#pragma unroll
        for (int t = 0; t < 12; t++) y[t] += qv * V[t];
    };

    // ---- S1: per-node 3x3 blocks of K (one-time atomics) + adjacency build ----
#pragma unroll
    for (int k = 0; k < 4; k++) {
        float b6[6] = {0,0,0,0,0,0};
#pragma unroll
        for (int a = 0; a < 3; a++) {
            float x0 = A[a][3*k], x1 = A[a][3*k+1], x2 = A[a][3*k+2];
            float s0 = S[a][3*k], s1 = S[a][3*k+1], s2 = S[a][3*k+2];
            b6[0] += cae*x0*x0 + cse*s0*s0;
            b6[1] += cae*x0*x1 + cse*s0*s1;
            b6[2] += cae*x0*x2 + cse*s0*s2;
            b6[3] += cae*x1*x1 + cse*s1*s1;
            b6[4] += cae*x1*x2 + cse*s1*s2;
            b6[5] += cae*x2*x2 + cse*s2*s2;
        }
        float v0 = V[3*k], v1 = V[3*k+1], v2 = V[3*k+2];
        b6[0] += cve*v0*v0; b6[1] += cve*v0*v1; b6[2] += cve*v0*v2;
        b6[3] += cve*v1*v1; b6[4] += cve*v1*v2; b6[5] += cve*v2*v2;
#pragma unroll
        for (int j = 0; j < 6; j++) atomicAdd(&blk6[nd4[k]*6 + j], b6[j]);
        unsigned pos = atomicAdd(&cnt[nd4[k]], 1u);
        if (pos < ADJCAP) adj[nd4[k] * ADJCAP + pos] = (unsigned)(tid * 4 + k);
    }
    flag_bar<true>(slots, 1);

    // ---- owners: masked inverse, r0/u0, publish mbuf = u0 (masked) ----
    const int own = blockIdx.x * 64 + threadIdx.x;   // exact: 32*64 = 2048
    const bool ownval = (threadIdx.x < 64);
    float iO[6] = {0,0,0,0,0,0};
    float maskO = 0.f;
    unsigned degO = 0;
    float xO[3]={0,0,0}, rO[3]={0,0,0}, uO[3]={0,0,0}, wO[3]={0,0,0}, mO[3]={0,0,0};
    float zO[3]={0,0,0}, qO[3]={0,0,0}, pO[3]={0,0,0}, sO[3]={0,0,0};
    if (ownval) {
        maskO = boundary[own] ? 0.f : 1.f;
        unsigned c = cnt[own];
        degO = c < ADJCAP ? c : ADJCAP;
        float s6[6];
#pragma unroll
        for (int j = 0; j < 6; j++) s6[j] = blk6[own*6 + j];
        float iv[6];
        sym_inv(s6, iv);
#pragma unroll
        for (int j = 0; j < 6; j++) iO[j] = iv[j] * maskO;
#pragma unroll
        for (int j = 0; j < 3; j++) rO[j] = bvec[3*own+j] * maskO;
        sym_apply(iO, rO, uO);
        vstore4(&mbuf[own*4], (f32x4){uO[0], uO[1], uO[2], 0.f});
    }
    flag_bar<true>(slots, 2);

    // ---- main loop: A (elements: y = Ke*m, private slots) / B (owners: gather+CG) ----
    unsigned tgt = 3;
    float gp = 1.f, ap = 1.f, stopv = 0.f;

    for (int k = 0; k <= NPH; k++) {
        // ===== A-phase: elements (stateless) =====
        {
            float pe[12];
#pragma unroll
            for (int kk = 0; kk < 4; kk++) {
                f32x4 mm = vload4(&mbuf[nd4[kk]*4]);
                pe[3*kk] = mm[0]; pe[3*kk+1] = mm[1]; pe[3*kk+2] = mm[2];
            }
            float y[12];
            matvec(pe, y);
#pragma unroll
            for (int kk = 0; kk < 4; kk++)
                vstore4(&ybuf[(tid*4+kk)*4], (f32x4){y[3*kk], y[3*kk+1], y[3*kk+2], 0.f});
        }
        flag_bar<false>(slots, tgt++);

        // ===== B-phase: owners =====
        if (ownval) {
            // issue y-slot gathers first (pipelined, independent)
            float n0 = 0.f, n1 = 0.f, n2 = 0.f;
            const unsigned* myadj = &adj[own * ADJCAP];
            for (unsigned j = 0; j < degO; j++) {
                unsigned enc = myadj[j];            // read-only, L1-cached
                f32x4 t = vload4(&ybuf[enc * 4]);
                n0 += t[0]; n1 += t[1]; n2 += t[2];
            }

            float gam = 0.f, del = 0.f, rho = 0.f, beta = 0.f, alpha = 0.f;
            if (k >= 1) {
                const float* db = gdot + ((k - 1) & 1) * 192;
                float g = aldf(&db[lane]);
                float d = aldf(&db[64 + lane]);
                float q = aldf(&db[128 + lane]);
                bfly3(g, d, q);
                gam = g; del = d; rho = q;
                if (lane == 0) sd[0] = rho;
                beta = (k == 1) ? 0.f : ((gp != 0.f) ? gam / gp : 0.f);
                float den = (k == 1) ? del : (del - beta * gam / ((ap != 0.f) ? ap : 1.f));
                alpha = (den != 0.f) ? gam / den : 0.f;
            }

            n0 *= maskO; n1 *= maskO; n2 *= maskO;
            if (k == 0) {
                wO[0] = n0; wO[1] = n1; wO[2] = n2;    // w0 = masked A u0
            } else {
                float nn[3] = {n0, n1, n2};
#pragma unroll
                for (int j = 0; j < 3; j++) {
                    zO[j] = nn[j] + beta * zO[j];
                    qO[j] = mO[j] + beta * qO[j];
                    pO[j] = uO[j] + beta * pO[j];
                    sO[j] = wO[j] + beta * sO[j];
                    xO[j] += alpha * pO[j];
                    rO[j] -= alpha * sO[j];
                    uO[j] -= alpha * qO[j];
                    wO[j] -= alpha * zO[j];
                }
                gp = gam; ap = alpha;
            }
            sym_apply(iO, wO, mO);
            vstore4(&mbuf[own*4], (f32x4){mO[0], mO[1], mO[2], 0.f});

            float gn = 0.f, dn = 0.f, qn = 0.f;
#pragma unroll
            for (int j = 0; j < 3; j++) {
                gn += rO[j]*uO[j]; dn += wO[j]*uO[j]; qn += rO[j]*rO[j];
            }
            bfly3(gn, dn, qn);
            if (lane == 0) {
                float* gpub = gdot + (k & 1) * 192;
                astf(&gpub[blockIdx.x], gn);
                astf(&gpub[64 + blockIdx.x], dn);
                astf(&gpub[128 + blockIdx.x], qn);
            }
        }
        flag_bar<false>(slots, tgt++);

        // uniform stop decision (sd written in B(k); identical across blocks)
        if (k >= 1) {
            float rr = sd[0];
            if (k == 1) stopv = rr * 4e-8f;        // rel residual 2e-4
            else if (rr <= stopv) break;
        }
    }

    if (ownval) {
#pragma unroll
        for (int j = 0; j < 3; j++) xout[3*own+j] = xO[j];
    }
}

extern "C" void kernel_launch(void* const* d_in, const int* in_sizes, int n_in,
                              void* d_out, int out_size, void* d_ws, size_t ws_size,
                              hipStream_t stream) {
    const float* theta = (const float*)d_in[0];
    const float* delta = (const float*)d_in[1];
    const float* ra    = (const float*)d_in[2];
    const float* rs    = (const float*)d_in[3];
    const float* rv    = (const float*)d_in[4];
    const float* vol   = (const float*)d_in[5];
    const float* b     = (const float*)d_in[6];
    const int* tets    = (const int*)d_in[7];
    const int* boundary = (const int*)d_in[8];
    float* x = (float*)d_out;
    float* ws = (float*)d_ws;

    hipMemsetAsync(ws, 0, WS_ZERO * sizeof(float), stream);
    pcg_kernel<<<dim3(NBLK), dim3(NTHR), 0, stream>>>(theta, delta, ra, rs, rv, vol, b,
                                                      tets, boundary, x, ws);
}

// Round 16
// 158.007 us; speedup vs baseline: 1.6725x; 1.6725x over previous
//
#include <hip/hip_runtime.h>

#define M_TETS 10240
#define N_NODES 2048
#define MAXPH 18
#define NBUF 20
#define NBLK 32
#define NTHR 320
#define SPIN_CAP 50000000

typedef float f32x4 __attribute__((ext_vector_type(4)));

// ws float offsets
#define OFF_VAL   12288                    // blk6: 6*2048 floats at 0
#define OFF_GDOT  (OFF_VAL + NBUF * 8192)  // ring of NBUF buffers, 2048 x float4 each
#define OFF_SLOT  (OFF_GDOT + 384)         // gdot: 2 sets x 3 x 64
#define WS_WORDS  (OFF_SLOT + 32)

// log(500), log(10000)
__device__ __constant__ float LOG_A_MIN_C = 6.2146080984221914f;
__device__ __constant__ float LOG_A_MAX_C = 9.2103403719761836f;

__device__ __forceinline__ void rel_fence() { __builtin_amdgcn_fence(__ATOMIC_RELEASE, "agent"); }
__device__ __forceinline__ void acq_fence() { __builtin_amdgcn_fence(__ATOMIC_ACQUIRE, "agent"); }
__device__ __forceinline__ unsigned aldu(const unsigned* p) {
    return __hip_atomic_load(p, __ATOMIC_RELAXED, __HIP_MEMORY_SCOPE_AGENT);
}
__device__ __forceinline__ float aldf(const float* p) {
    return __hip_atomic_load(p, __ATOMIC_RELAXED, __HIP_MEMORY_SCOPE_AGENT);
}
__device__ __forceinline__ void astf(float* p, float v) {
    __hip_atomic_store(p, v, __ATOMIC_RELAXED, __HIP_MEMORY_SCOPE_AGENT);
}
__device__ __forceinline__ void astu(unsigned* p, unsigned v) {
    __hip_atomic_store(p, v, __ATOMIC_RELAXED, __HIP_MEMORY_SCOPE_AGENT);
}

// coherence-point 16B load (R12/R14-proven: observes remote agent-atomic
// stores across XCDs with no fences)
__device__ __forceinline__ f32x4 vload4(const float* p) {
    return *(volatile const f32x4*)p;
}

// Flag barrier. FULL=true: full release/acquire fences (setup only).
// FULL=false: fence-free — in-loop writes are all agent atomics (performed at
// the coherence point); release ordering = s_waitcnt vmcnt(0) before the flag
// store; reads after the barrier use volatile/atomic ops, so no inv needed.
template<bool FULL>
__device__ __forceinline__ void flag_bar(unsigned* slots, unsigned tgt) {
    if (FULL) rel_fence();
    else asm volatile("s_waitcnt vmcnt(0)" ::: "memory");
    __syncthreads();
    if (threadIdx.x == 0) astu(&slots[blockIdx.x], tgt);
    if (threadIdx.x < NBLK) {
        int guard = 0;
        while (aldu(&slots[threadIdx.x]) < tgt && ++guard < SPIN_CAP) {}
    }
    __syncthreads();
    if (FULL) acq_fence();
    else asm volatile("" ::: "memory");
}

__device__ __forceinline__ void bfly3(float& a, float& b, float& c) {
#pragma unroll
    for (int off = 32; off > 0; off >>= 1) {
        a += __shfl_xor(a, off);
        b += __shfl_xor(b, off);
        c += __shfl_xor(c, off);
    }
}

// symmetric 3x3 apply: s6 = [00,01,02,11,12,22]
__device__ __forceinline__ void sym_apply(const float* s6, const float* v, float* out) {
    out[0] = s6[0]*v[0] + s6[1]*v[1] + s6[2]*v[2];
    out[1] = s6[1]*v[0] + s6[3]*v[1] + s6[4]*v[2];
    out[2] = s6[2]*v[0] + s6[4]*v[1] + s6[5]*v[2];
}

__device__ __forceinline__ void sym_inv(const float* s, float* o) {
    float a = s[0], b = s[1], c = s[2], d = s[3], e = s[4], f = s[5];
    float C00 = d*f - e*e, C01 = c*e - b*f, C02 = b*e - c*d;
    float id = 1.0f / (a*C00 + b*C01 + c*C02);
    o[0] = C00*id; o[1] = C01*id; o[2] = C02*id;
    o[3] = (a*f - c*c)*id; o[4] = (b*c - a*e)*id; o[5] = (a*d - b*b)*id;
}

__global__ void __launch_bounds__(NTHR, 1) pcg_kernel(
    const float* __restrict__ theta, const float* __restrict__ delta,
    const float* __restrict__ ra, const float* __restrict__ rs, const float* __restrict__ rv,
    const float* __restrict__ vol, const float* __restrict__ bvec,
    const int* __restrict__ tets, const int* __restrict__ boundary,
    float* __restrict__ xout, float* __restrict__ ws)
{
    const int tid = blockIdx.x * NTHR + threadIdx.x;   // element id, 10240 total
    const int lane = threadIdx.x & 63;
    __shared__ float sd[3];

    float*    blk6  = ws;
    float*    val   = ws + OFF_VAL;
    float*    gdot  = ws + OFF_GDOT;
    unsigned* slots = (unsigned*)(ws + OFF_SLOT);

    // ---- element data -> registers (ws pre-zeroed by hipMemsetAsync) ----
    float A[3][12], S[3][12], V[12];
    int nd4[4];
    float cae, cse, cve;
    {
        const int e = tid;
#pragma unroll
        for (int a = 0; a < 3; a++)
#pragma unroll
            for (int i = 0; i < 12; i++) {
                A[a][i] = ra[e * 36 + a * 12 + i];
                S[a][i] = rs[e * 36 + a * 12 + i];
            }
#pragma unroll
        for (int i = 0; i < 12; i++) V[i] = rv[e * 12 + i];
        const int4 t = reinterpret_cast<const int4*>(tets)[e];
        nd4[0] = t.x; nd4[1] = t.y; nd4[2] = t.z; nd4[3] = t.w;
        float la = theta[0] + delta[e];
        la = fminf(fmaxf(la, LOG_A_MIN_C), LOG_A_MAX_C);
        float al = expf(la);
        float v = vol[e];
        cae = v * al; cse = 2.0f * v * al; cve = 8.0f * v * al;
    }

    auto matvec = [&](const float* pe, float* y) {
#pragma unroll
        for (int t = 0; t < 12; t++) y[t] = 0.f;
#pragma unroll
        for (int a = 0; a < 3; a++) {
            float qa = 0.f, qs = 0.f;
#pragma unroll
            for (int t = 0; t < 12; t++) { qa += A[a][t] * pe[t]; qs += S[a][t] * pe[t]; }
            qa *= cae; qs *= cse;
#pragma unroll
            for (int t = 0; t < 12; t++) y[t] += qa * A[a][t] + qs * S[a][t];
        }
        float qv = 0.f;
#pragma unroll
        for (int t = 0; t < 12; t++) qv += V[t] * pe[t];
        qv *= cve;
#pragma unroll
        for (int t = 0; t < 12; t++) y[t] += qv * V[t];
    };

    // ---- S1: accumulate symmetric per-node 3x3 blocks of K ----
#pragma unroll
    for (int k = 0; k < 4; k++) {
        float b6[6] = {0,0,0,0,0,0};
#pragma unroll
        for (int a = 0; a < 3; a++) {
            float x0 = A[a][3*k], x1 = A[a][3*k+1], x2 = A[a][3*k+2];
            float s0 = S[a][3*k], s1 = S[a][3*k+1], s2 = S[a][3*k+2];
            b6[0] += cae*x0*x0 + cse*s0*s0;
            b6[1] += cae*x0*x1 + cse*s0*s1;
            b6[2] += cae*x0*x2 + cse*s0*s2;
            b6[3] += cae*x1*x1 + cse*s1*s1;
            b6[4] += cae*x1*x2 + cse*s1*s2;
            b6[5] += cae*x2*x2 + cse*s2*s2;
        }
        float v0 = V[3*k], v1 = V[3*k+1], v2 = V[3*k+2];
        b6[0] += cve*v0*v0; b6[1] += cve*v0*v1; b6[2] += cve*v0*v2;
        b6[3] += cve*v1*v1; b6[4] += cve*v1*v2; b6[5] += cve*v2*v2;
#pragma unroll
        for (int j = 0; j < 6; j++) atomicAdd(&blk6[nd4[k]*6 + j], b6[j]);
    }
    flag_bar<true>(slots, 1);

    // ---- local inverses: elements (masked, per node) and owners ----
    float ib[4][6], nmask4[4];
#pragma unroll
    for (int k = 0; k < 4; k++) {
        float bm = boundary[nd4[k]] ? 0.f : 1.f;
        nmask4[k] = bm;
        float s6[6];
#pragma unroll
        for (int j = 0; j < 6; j++) s6[j] = blk6[nd4[k]*6 + j];
        float iv[6];
        sym_inv(s6, iv);
#pragma unroll
        for (int j = 0; j < 6; j++) ib[k][j] = iv[j] * bm;
    }

    const int own = blockIdx.x * 64 + threadIdx.x;   // exact: 32*64 = 2048
    const bool ownval = (threadIdx.x < 64);
    float iO[6] = {0,0,0,0,0,0};
    float maskO = 0.f;
    float xO[3]={0,0,0}, rO[3]={0,0,0}, uO[3]={0,0,0}, wO[3]={0,0,0}, mO[3]={0,0,0};
    float zO[3]={0,0,0}, qO[3]={0,0,0}, pO[3]={0,0,0}, sO[3]={0,0,0};
    if (ownval) {
        maskO = boundary[own] ? 0.f : 1.f;
        float s6[6];
#pragma unroll
        for (int j = 0; j < 6; j++) s6[j] = blk6[own*6 + j];
        float iv[6];
        sym_inv(s6, iv);
#pragma unroll
        for (int j = 0; j < 6; j++) iO[j] = iv[j] * maskO;
#pragma unroll
        for (int j = 0; j < 3; j++) rO[j] = bvec[3*own+j] * maskO;
        sym_apply(iO, rO, uO);
    }

    // ---- phase -1: scatter A*u0 into ring[0] ----
    {
        float u0e[12];
#pragma unroll
        for (int k = 0; k < 4; k++) {
            float bb[3] = { bvec[3*nd4[k]], bvec[3*nd4[k]+1], bvec[3*nd4[k]+2] };
            sym_apply(ib[k], bb, &u0e[3*k]);
        }
        float y[12];
        matvec(u0e, y);
        float* v0 = val;                     // ring[0]
#pragma unroll
        for (int kk = 0; kk < 4; kk++)
#pragma unroll
            for (int c = 0; c < 3; c++) atomicAdd(&v0[4*nd4[kk]+c], y[3*kk+c]);
    }
    flag_bar<false>(slots, 2);

    // ---- phase 0: consume ring[0] (w0); init replicas/owner; scatter A*m0 -> ring[1] ----
    float w_e[12], z_e[12];
    {
        const float* vR = val;               // ring[0]
#pragma unroll
        for (int kk = 0; kk < 4; kk++) {
            f32x4 t = vload4(&vR[4*nd4[kk]]);
            w_e[3*kk]   = t[0] * nmask4[kk];
            w_e[3*kk+1] = t[1] * nmask4[kk];
            w_e[3*kk+2] = t[2] * nmask4[kk];
            z_e[3*kk] = 0.f; z_e[3*kk+1] = 0.f; z_e[3*kk+2] = 0.f;
        }
        float me[12];
#pragma unroll
        for (int kk = 0; kk < 4; kk++) sym_apply(ib[kk], &w_e[3*kk], &me[3*kk]);
        float y[12];
        matvec(me, y);
        float* vS = val + 8192;              // ring[1]
#pragma unroll
        for (int kk = 0; kk < 4; kk++)
#pragma unroll
            for (int c = 0; c < 3; c++) atomicAdd(&vS[4*nd4[kk]+c], y[3*kk+c]);

        if (ownval) {
            float gn = 0.f, dn = 0.f, qn = 0.f;
            f32x4 t = vload4(&vR[4*own]);
            wO[0] = t[0] * maskO; wO[1] = t[1] * maskO; wO[2] = t[2] * maskO;
            sym_apply(iO, wO, mO);
#pragma unroll
            for (int j = 0; j < 3; j++) {
                gn += rO[j]*uO[j]; dn += wO[j]*uO[j]; qn += rO[j]*rO[j];
            }
            bfly3(gn, dn, qn);
            if (threadIdx.x == 0) {
                astf(&gdot[blockIdx.x], gn);
                astf(&gdot[64 + blockIdx.x], dn);
                astf(&gdot[128 + blockIdx.x], qn);
            }
        }
    }
    flag_bar<false>(slots, 3);

    // ---- main loop: one phase, one fence-free barrier per iteration.
    //      ring[k] = read, ring[k+1] = scatter target (pre-zeroed, first use).
    float gp = 1.f, ap = 1.f, stop = 0.f;
    unsigned tgt = 4;

    for (int k = 1; k <= MAXPH; k++) {
        const float* vR = val + k * 8192;

        // gather n early (coherence point; overlaps dot completion)
        float ne[12];
#pragma unroll
        for (int kk = 0; kk < 4; kk++) {
            f32x4 t = vload4(&vR[4*nd4[kk]]);
            ne[3*kk]   = t[0] * nmask4[kk];
            ne[3*kk+1] = t[1] * nmask4[kk];
            ne[3*kk+2] = t[2] * nmask4[kk];
        }
        float nO[3] = {0,0,0};
        if (ownval) {
            f32x4 t = vload4(&vR[4*own]);
            nO[0] = t[0] * maskO; nO[1] = t[1] * maskO; nO[2] = t[2] * maskO;
        }

        // cross-block dot completion (wave 0; slots 32..63 are zero-padding)
        if (threadIdx.x < 64) {
            const float* dbase = gdot + ((k - 1) & 1) * 192;
            float g0 = aldf(&dbase[lane]);
            float d0 = aldf(&dbase[64 + lane]);
            float q0 = aldf(&dbase[128 + lane]);
            bfly3(g0, d0, q0);
            if (threadIdx.x == 0) { sd[0] = g0; sd[1] = d0; sd[2] = q0; }
        }
        __syncthreads();
        float gam = sd[0], del = sd[1], rho = sd[2];

        if (k == 1) stop = rho * 4e-8f;      // rel residual 2e-4
        else if (rho <= stop) break;         // uniform across grid
        float beta  = (k == 1) ? 0.f : ((gp != 0.f) ? gam / gp : 0.f);
        float den   = (k == 1) ? del : (del - beta * gam / ((ap != 0.f) ? ap : 1.f));
        float alpha = (den != 0.f) ? gam / den : 0.f;

        // element replica update + matvec + scatter into ring[k+1]
        {
#pragma unroll
            for (int t = 0; t < 12; t++) {
                z_e[t] = ne[t] + beta * z_e[t];
                w_e[t] -= alpha * z_e[t];
            }
            float me[12];
#pragma unroll
            for (int kk = 0; kk < 4; kk++) sym_apply(ib[kk], &w_e[3*kk], &me[3*kk]);
            float y[12];
            matvec(me, y);
            float* vS = val + (k + 1) * 8192;
#pragma unroll
            for (int kk = 0; kk < 4; kk++)
#pragma unroll
                for (int c = 0; c < 3; c++) atomicAdd(&vS[4*nd4[kk]+c], y[3*kk+c]);
        }

        // owner recurrences + dot publish (no buffer zeroing — ring is pre-zeroed)
        if (ownval) {
            float gn = 0.f, dn = 0.f, qn = 0.f;
#pragma unroll
            for (int j = 0; j < 3; j++) {
                zO[j] = nO[j] + beta * zO[j];
                qO[j] = mO[j] + beta * qO[j];
                pO[j] = uO[j] + beta * pO[j];
                sO[j] = wO[j] + beta * sO[j];
                xO[j] += alpha * pO[j];
                rO[j] -= alpha * sO[j];
                uO[j] -= alpha * qO[j];
                wO[j] -= alpha * zO[j];
            }
            sym_apply(iO, wO, mO);
#pragma unroll
            for (int j = 0; j < 3; j++) {
                gn += rO[j]*uO[j]; dn += wO[j]*uO[j]; qn += rO[j]*rO[j];
            }
            bfly3(gn, dn, qn);
            float* gd_pub = gdot + (k & 1) * 192;
            if (threadIdx.x == 0) {
                astf(&gd_pub[blockIdx.x], gn);
                astf(&gd_pub[64 + blockIdx.x], dn);
                astf(&gd_pub[128 + blockIdx.x], qn);
            }
        }

        gp = gam; ap = alpha;
        flag_bar<false>(slots, tgt++);
    }

    if (ownval) {
#pragma unroll
        for (int j = 0; j < 3; j++) xout[3*own+j] = xO[j];
    }
}

extern "C" void kernel_launch(void* const* d_in, const int* in_sizes, int n_in,
                              void* d_out, int out_size, void* d_ws, size_t ws_size,
                              hipStream_t stream) {
    const float* theta = (const float*)d_in[0];
    const float* delta = (const float*)d_in[1];
    const float* ra    = (const float*)d_in[2];
    const float* rs    = (const float*)d_in[3];
    const float* rv    = (const float*)d_in[4];
    const float* vol   = (const float*)d_in[5];
    const float* b     = (const float*)d_in[6];
    const int* tets    = (const int*)d_in[7];
    const int* boundary = (const int*)d_in[8];
    float* x = (float*)d_out;
    float* ws = (float*)d_ws;

    hipMemsetAsync(ws, 0, WS_WORDS * sizeof(float), stream);
    pcg_kernel<<<dim3(NBLK), dim3(NTHR), 0, stream>>>(theta, delta, ra, rs, rv, vol, b,
                                                      tets, boundary, x, ws);
}